// Round 7
// baseline (138.991 us; speedup 1.0000x reference)
//
#include <hip/hip_runtime.h>
#include <cstdint>
#include <cstddef>

#define NPTS 8192
#define NUM_CLASSES 5
#define XCOLS 10          // 3 coords + batch + feat + 5 seg
#define EPS2 225.0f
#define MIN_PTS 5
#define NGROUPS 10
#define BIGC 0x3fffffff

#define BANDS 8           // row bands of 1024 rows, one edge region + counter each
#define BANDROWS 1024
#define BANDCAP 32768     // edges per band region (expect ~6.7k)
#define CPAD 64           // counters padded 64 ints (256 B) apart
#define JT 32             // cols staged per k_adj block
#define RPT 4             // rows per thread

#define GSL 16384         // per-group core-core slice cap (global)
#define GSB 4096          // per-group core-noncore slice cap (global)
#define ELCAP 8192        // LDS core-core edge cap (expect ~5.4k)
#define EBCAP 2048        // LDS border edge cap (expect ~500)
#define NLCAP 1280        // group node list cap (expect ~820)
#define ROUNDS 24

// ---------------- setup: pack coords+p2, group, init deg + counters ----------
__global__ void k_setup(const float* __restrict__ x, float4* __restrict__ q,
                        int* __restrict__ grp, int* __restrict__ deg,
                        unsigned int* __restrict__ bandcnt,
                        unsigned int* __restrict__ glcnt,
                        unsigned int* __restrict__ gbcnt) {
    int i = blockIdx.x * blockDim.x + threadIdx.x;
    if (i < BANDS * CPAD) bandcnt[i] = 0u;
    if (i < NGROUPS * CPAD) { glcnt[i] = 0u; gbcnt[i] = 0u; }
    if (i >= NPTS) return;
    const float* r = x + (size_t)i * XCOLS;
    float px = r[0], py = r[1], pz = r[2];
    int b = (int)r[3];
    float best = r[5]; int bc = 0;
    #pragma unroll
    for (int c = 1; c < NUM_CLASSES; c++) {
        float v = r[5 + c];
        if (v > best) { best = v; bc = c; }   // strict > keeps first max (jnp.argmax)
    }
    q[i] = make_float4(px, py, pz, px*px + py*py + pz*pz);
    grp[i] = b * NUM_CLASSES + bc;
    deg[i] = 1;          // self-adjacency (d2=0 < EPS2, same group)
}

// ---------------- adjacency -> banded edge list (j>i) + degree ---------------
// unchanged from R6 (block-aggregated band-counter emission)
__global__ void __launch_bounds__(256) k_adj(
        const float4* __restrict__ q, const int* __restrict__ grp,
        unsigned int* __restrict__ edges, unsigned int* __restrict__ bandcnt,
        int* __restrict__ deg) {
    int rt = blockIdx.x >> 8;        // 0..7 row band
    int cs = blockIdx.x & 255;       // 0..255 col slice
    int i0 = rt * BANDROWS;
    int j0 = cs * JT;
    if (j0 + JT - 1 <= i0) return;   // no j>i possible in this block

    __shared__ float4 qs[JT];
    __shared__ int    gs[JT];
    __shared__ int    warr[4], woff[4], bbase_s;
    int tid = threadIdx.x;
    if (tid < JT) { qs[tid] = q[j0 + tid]; gs[tid] = grp[j0 + tid]; }
    __syncthreads();

    float4 qi[RPT]; int gi[RPT]; int irow[RPT];
    #pragma unroll
    for (int r = 0; r < RPT; r++) {
        irow[r] = i0 + tid + 256 * r;
        qi[r] = q[irow[r]];
        gi[r] = grp[irow[r]];
    }

    unsigned int bits[RPT] = {0u, 0u, 0u, 0u};
    #pragma unroll
    for (int t = 0; t < JT; t++) {
        float4 qj = qs[t]; int gj = gs[t];          // wave-uniform broadcast
        #pragma unroll
        for (int r = 0; r < RPT; r++) {
            float d2 = qi[r].w + qj.w - 2.0f * (qi[r].x*qj.x + qi[r].y*qj.y + qi[r].z*qj.z);
            bool a = (gi[r] == gj) && (d2 < EPS2);
            bits[r] |= a ? (1u << t) : 0u;
        }
    }

    int rc[RPT]; int cnt = 0;
    #pragma unroll
    for (int r = 0; r < RPT; r++) {
        int d = irow[r] - j0;                        // keep bits with j > irow
        unsigned int m = (d < 0) ? 0xffffffffu : ((d >= JT - 1) ? 0u : (0xffffffffu << (d + 1)));
        bits[r] &= m;
        rc[r] = __popc(bits[r]);
        cnt += rc[r];
    }

    int lane = tid & 63, wv = tid >> 6;
    int incl = cnt;
    #pragma unroll
    for (int d = 1; d < 64; d <<= 1) {
        int o = __shfl_up(incl, d);
        if (lane >= d) incl += o;
    }
    if (lane == 63) warr[wv] = incl;
    __syncthreads();
    if (tid == 0) {
        int acc = 0;
        #pragma unroll
        for (int w = 0; w < 4; w++) { woff[w] = acc; acc += warr[w]; }
        bbase_s = (acc > 0) ? (int)atomicAdd(&bandcnt[rt * CPAD], (unsigned int)acc) : 0;
    }
    __syncthreads();

    int pos = bbase_s + woff[wv] + (incl - cnt);
    unsigned int* eg = edges + (size_t)rt * BANDCAP;
    #pragma unroll
    for (int r = 0; r < RPT; r++) {
        if (rc[r] > 0) {
            atomicAdd(&deg[irow[r]], rc[r]);
            unsigned int tag = ((unsigned int)gi[r] << 26) | ((unsigned int)irow[r] << 13);
            unsigned int b = bits[r];
            while (b) {
                int bb = __ffs(b) - 1;
                b &= b - 1;
                int j = j0 + bb;
                if (pos < BANDCAP) eg[pos] = tag | (unsigned int)j;
                pos++;
                atomicAdd(&deg[j], 1);
            }
        }
    }
}

// ---------------- bucket: banded edges -> per-group L/B slices (ONE pass) ----
__global__ void __launch_bounds__(256) k_bucket(
        const unsigned int* __restrict__ edges, const unsigned int* __restrict__ bandcnt,
        const int* __restrict__ deg,
        unsigned int* __restrict__ eLg, unsigned int* __restrict__ eBg,
        unsigned int* __restrict__ glcnt, unsigned int* __restrict__ gbcnt) {
    int tid = threadIdx.x, lane = tid & 63;
    int gstride = gridDim.x * 256;
    for (int b = 0; b < BANDS; b++) {
        unsigned int Eu = bandcnt[b * CPAD];
        int E = (Eu > (unsigned)BANDCAP) ? BANDCAP : (int)Eu;
        const unsigned int* eg = edges + (size_t)b * BANDCAP;
        for (int e0 = blockIdx.x * 256; e0 < E; e0 += gstride) {
            int e = e0 + tid;
            unsigned int pk = (e < E) ? eg[e] : 0u;
            bool val = (e < E);
            int u = (int)((pk >> 13) & 8191u), v = (int)(pk & 8191u);
            bool cu = val && (deg[u] >= MIN_PTS);
            bool cv = val && (deg[v] >= MIN_PTS);
            bool isL = cu && cv;
            bool isB = val && (cu != cv);
            int ge = (int)(pk >> 26);
            unsigned long long rem = __ballot(isL || isB);
            while (rem) {
                int src = __ffsll((long long)rem) - 1;
                int gcur = __shfl(ge, src);
                bool mL = isL && (ge == gcur);
                bool mB = isB && (ge == gcur);
                unsigned long long bL = __ballot(mL), bB = __ballot(mB);
                int cL = __popcll(bL), cB = __popcll(bB);
                unsigned int baseL = 0, baseB = 0;
                if (lane == src) {
                    if (cL) baseL = atomicAdd(&glcnt[gcur * CPAD], (unsigned int)cL);
                    if (cB) baseB = atomicAdd(&gbcnt[gcur * CPAD], (unsigned int)cB);
                }
                baseL = __shfl(baseL, src); baseB = __shfl(baseB, src);
                if (mL) {
                    unsigned int idx = baseL + (unsigned int)__popcll(bL & ((1ull << lane) - 1ull));
                    if (idx < GSL) eLg[(size_t)gcur * GSL + idx] = pk & 0x3ffffffu;
                }
                if (mB) {
                    unsigned int idx = baseB + (unsigned int)__popcll(bB & ((1ull << lane) - 1ull));
                    if (idx < GSB) eBg[(size_t)gcur * GSB + idx] = pk & 0x3ffffffu;
                }
                rem &= ~__ballot(ge == gcur);
            }
        }
    }
}

// ---------------- per-group: SV rounds + rank + border + final ---------------
// one block (1024 thr) per group; reads ONLY its own compact edge slices.
__global__ void __launch_bounds__(1024) k_group(
        const unsigned int* __restrict__ eLg, const unsigned int* __restrict__ eBg,
        const unsigned int* __restrict__ glcnt, const unsigned int* __restrict__ gbcnt,
        const int* __restrict__ deg, const int* __restrict__ grp,
        const float* __restrict__ x, float* __restrict__ out) {
    __shared__ int spar[NPTS];                       // labels -> later ccid (32 KB)
    __shared__ int sbuf[NPTS];                       // scid then border-min (32 KB)
    __shared__ unsigned int eL[ELCAP];               // 32 KB
    __shared__ unsigned int eB[EBCAP];               // 8 KB
    __shared__ unsigned long long corebm[NPTS/64];   // 1 KB
    __shared__ unsigned long long gbm[NPTS/64];      // 1 KB
    __shared__ unsigned long long repbm[NPTS/64];    // 1 KB
    __shared__ int nlist[NLCAP];                     // 5 KB
    __shared__ int nNodes, sflag, wpart[16];

    int g = blockIdx.x;
    int tid = threadIdx.x, lane = tid & 63, wv = tid >> 6;

    if (tid == 0) nNodes = 0;
    for (int i = tid; i < NPTS; i += 1024) spar[i] = i;
    __syncthreads();
    // core / group bitmaps + compact node list (ballot, wave-aggregated)
    for (int w = wv; w < NPTS / 64; w += 16) {
        int i = w * 64 + lane;
        bool isc = deg[i] >= MIN_PTS;
        bool ing = grp[i] == g;
        unsigned long long cb = __ballot(isc);
        unsigned long long gb = __ballot(ing);
        if (lane == 0) { corebm[w] = cb; gbm[w] = gb; }
        int cnt = __popcll(gb);
        if (cnt) {
            int base = 0;
            if (lane == 0) base = atomicAdd(&nNodes, cnt);
            base = __shfl(base, 0);
            if (ing) nlist[base + __popcll(gb & ((1ull << lane) - 1ull))] = i;
        }
    }
    // load this group's edge slices into LDS
    unsigned int NLu = glcnt[g * CPAD]; if (NLu > (unsigned)GSL) NLu = GSL;
    unsigned int NBu = gbcnt[g * CPAD]; if (NBu > (unsigned)GSB) NBu = GSB;
    int NL = (NLu > (unsigned)ELCAP) ? ELCAP : (int)NLu;
    int NB = (NBu > (unsigned)EBCAP) ? EBCAP : (int)NBu;
    for (int k = tid; k < NL; k += 1024) eL[k] = eLg[(size_t)g * GSL + k];
    for (int k = tid; k < NB; k += 1024) eB[k] = eBg[(size_t)g * GSB + k];
    __syncthreads();
    int NN = nNodes; if (NN > NLCAP) NN = NLCAP;

    auto corebit = [&](int v) -> bool { return (corebm[v >> 6] >> (v & 63)) & 1ull; };

    // SV rounds: hook-to-min (core-core edges) + pointer jump (group nodes)
    for (int r = 0; r < ROUNDS; r++) {
        if (tid == 0) sflag = 0;
        __syncthreads();
        for (int k = tid; k < NL; k += 1024) {
            unsigned int pk = eL[k];
            int u = (int)(pk >> 13), v = (int)(pk & 8191u);
            int a = spar[u], b2 = spar[v];
            if (a < b2)      { int old = atomicMin(&spar[v], a);  if (old > a)  sflag = 1; }
            else if (b2 < a) { int old = atomicMin(&spar[u], b2); if (old > b2) sflag = 1; }
        }
        __syncthreads();
        for (int k = tid; k < NN; k += 1024) {
            int i = nlist[k];
            int s = spar[i]; int s2 = spar[s];
            if (s2 < s) { spar[i] = s2; sflag = 1; }
        }
        __syncthreads();
        if (!sflag) break;
    }

    // rep bitmap (core, in-group, fixpoint) + hierarchical rank
    for (int w = wv; w < NPTS / 64; w += 16) {
        int i = w * 64 + lane;
        bool isr = ((corebm[w] & gbm[w]) >> lane & 1ull) && (spar[i] == i);
        unsigned long long bm = __ballot(isr);
        if (lane == 0) repbm[w] = bm;
    }
    __syncthreads();
    if (lane == 0) {
        int s = 0;
        #pragma unroll
        for (int k = 0; k < 8; k++) s += __popcll(repbm[wv * 8 + k]);
        wpart[wv] = s;
    }
    __syncthreads();
    if (tid == 0) {
        int acc = 0;
        #pragma unroll
        for (int w = 0; w < 16; w++) { int t = wpart[w]; wpart[w] = acc; acc += t; }
    }
    __syncthreads();
    {
        int running = wpart[wv];
        #pragma unroll
        for (int k = 0; k < 8; k++) {
            unsigned long long bb = repbm[wv * 8 + k];
            if ((bb >> lane) & 1ull)
                sbuf[(wv * 8 + k) * 64 + lane] = running + __popcll(bb & ((1ull << lane) - 1ull));
            running += __popcll(bb);
        }
    }
    __syncthreads();
    // ccid for group nodes -> overwrite spar; then sbuf -> border-min init
    int cc[2]; int ni[2];
    #pragma unroll
    for (int t = 0; t < 2; t++) {
        int k = tid + t * 1024;
        ni[t] = (k < NN) ? nlist[k] : -1;
        cc[t] = (ni[t] >= 0 && corebit(ni[t])) ? sbuf[spar[ni[t]]] : BIGC;
    }
    __syncthreads();
    #pragma unroll
    for (int t = 0; t < 2; t++) {
        if (ni[t] >= 0) { spar[ni[t]] = cc[t]; sbuf[ni[t]] = BIGC; }
    }
    __syncthreads();
    // border: min adjacent core cid for non-core endpoints
    for (int k = tid; k < NB; k += 1024) {
        unsigned int pk = eB[k];
        int u = (int)(pk >> 13), v = (int)(pk & 8191u);
        int cu = spar[u], cv = spar[v];
        if (cu == BIGC && cv != BIGC)      atomicMin(&sbuf[u], cv);
        else if (cv == BIGC && cu != BIGC) atomicMin(&sbuf[v], cu);
    }
    __syncthreads();
    // final labels + clustered output for this group's nodes
    #pragma unroll
    for (int t = 0; t < 2; t++) {
        int i = ni[t];
        if (i < 0) continue;
        int c = spar[i];
        int lbl = (c != BIGC) ? c : ((sbuf[i] < BIGC) ? sbuf[i] : -1);
        out[i] = (float)lbl;
        const float* r = x + (size_t)i * XCOLS;
        float* o = out + NPTS + (size_t)i * 5;
        bool keep = lbl >= 0;
        #pragma unroll
        for (int c5 = 0; c5 < 5; c5++) o[c5] = keep ? r[c5] : 0.0f;
    }
}

extern "C" void kernel_launch(void* const* d_in, const int* in_sizes, int n_in,
                              void* d_out, int out_size, void* d_ws, size_t ws_size,
                              hipStream_t stream) {
    const float* x = (const float*)d_in[0];
    float* out = (float*)d_out;
    char* ws = (char*)d_ws;

    // workspace layout (~2 MB)
    float4* q            = (float4*)(ws);                   // 131072 B
    int* grp             = (int*)(ws + 131072);             // 32768
    int* deg             = (int*)(ws + 163840);             // 32768
    unsigned int* bandcnt= (unsigned int*)(ws + 196608);    // 2048
    unsigned int* glcnt  = (unsigned int*)(ws + 198656);    // 2560
    unsigned int* gbcnt  = (unsigned int*)(ws + 201216);    // 2560
    unsigned int* edges  = (unsigned int*)(ws + 203776);    // 8*32768*4 = 1 MB
    unsigned int* eLg    = (unsigned int*)(ws + 1252352);   // 10*16384*4 = 640 KB
    unsigned int* eBg    = (unsigned int*)(ws + 1907712);   // 10*4096*4 = 160 KB

    k_setup <<<NPTS / 256, 256, 0, stream>>>(x, q, grp, deg, bandcnt, glcnt, gbcnt);
    k_adj   <<<BANDS * 256, 256, 0, stream>>>(q, grp, edges, bandcnt, deg);
    k_bucket<<<64, 256, 0, stream>>>(edges, bandcnt, deg, eLg, eBg, glcnt, gbcnt);
    k_group <<<NGROUPS, 1024, 0, stream>>>(eLg, eBg, glcnt, gbcnt, deg, grp, x, out);
}

// Round 8
// 112.150 us; speedup vs baseline: 1.2393x; 1.2393x over previous
//
#include <hip/hip_runtime.h>
#include <cstdint>
#include <cstddef>

#define NPTS 8192
#define NUM_CLASSES 5
#define XCOLS 10          // 3 coords + batch + feat + 5 seg
#define EPS2 225.0f
#define MIN_PTS 5
#define NGROUPS 10
#define BIGC 0x3fffffff

#define BANDS 8           // row bands of 1024 rows
#define BANDROWS 1024
#define REGCAP 8192       // edges per (band,group) region (expect ~675)
#define CPAD 64           // counters padded 64 ints (256 B) apart
#define JT 32             // cols staged per k_adj block
#define RPT 4             // rows per thread

#define ELCAP 8192        // LDS core-core edge cap (expect ~5.4k)
#define EBCAP 2048        // LDS border edge cap (expect ~500)
#define NLCAP 1280        // group node list cap (expect ~820)
#define ROUNDS 24

// ---------------- setup: pack coords+p2, group, init deg + counters ----------
__global__ void k_setup(const float* __restrict__ x, float4* __restrict__ q,
                        int* __restrict__ grp, int* __restrict__ deg,
                        unsigned int* __restrict__ gcnt) {
    int i = blockIdx.x * blockDim.x + threadIdx.x;
    if (i < BANDS * NGROUPS * CPAD) gcnt[i] = 0u;
    if (i >= NPTS) return;
    const float* r = x + (size_t)i * XCOLS;
    float px = r[0], py = r[1], pz = r[2];
    int b = (int)r[3];
    float best = r[5]; int bc = 0;
    #pragma unroll
    for (int c = 1; c < NUM_CLASSES; c++) {
        float v = r[5 + c];
        if (v > best) { best = v; bc = c; }   // strict > keeps first max (jnp.argmax)
    }
    q[i] = make_float4(px, py, pz, px*px + py*py + pz*pz);
    grp[i] = b * NUM_CLASSES + bc;
    deg[i] = 1;          // self-adjacency (d2=0 < EPS2, same group)
}

// ---------------- adjacency -> per-(band,group) edge slices (j>i) + degree ---
// grid = 8 row-bands x 256 col-slices; block 256 thr; thread owns 4 rows x 32 cols.
// Emission: LDS per-group block counters -> <=10 padded global reserves/block.
__global__ void __launch_bounds__(256) k_adj(
        const float4* __restrict__ q, const int* __restrict__ grp,
        unsigned int* __restrict__ edges, unsigned int* __restrict__ gcnt,
        int* __restrict__ deg) {
    int rt = blockIdx.x >> 8;        // 0..7 row band
    int cs = blockIdx.x & 255;       // 0..255 col slice
    int i0 = rt * BANDROWS;
    int j0 = cs * JT;
    if (j0 + JT - 1 <= i0) return;   // no j>i possible in this block

    __shared__ float4 qs[JT];
    __shared__ int    gs[JT];
    __shared__ unsigned int lcnt[NGROUPS], lbase[NGROUPS];
    int tid = threadIdx.x;
    if (tid < JT) { qs[tid] = q[j0 + tid]; gs[tid] = grp[j0 + tid]; }
    if (tid < NGROUPS) lcnt[tid] = 0u;
    __syncthreads();

    float4 qi[RPT]; int gi[RPT]; int irow[RPT];
    #pragma unroll
    for (int r = 0; r < RPT; r++) {
        irow[r] = i0 + tid + 256 * r;
        qi[r] = q[irow[r]];
        gi[r] = grp[irow[r]];
    }

    unsigned int bits[RPT] = {0u, 0u, 0u, 0u};
    #pragma unroll
    for (int t = 0; t < JT; t++) {
        float4 qj = qs[t]; int gj = gs[t];          // wave-uniform broadcast
        #pragma unroll
        for (int r = 0; r < RPT; r++) {
            float d2 = qi[r].w + qj.w - 2.0f * (qi[r].x*qj.x + qi[r].y*qj.y + qi[r].z*qj.z);
            bool a = (gi[r] == gj) && (d2 < EPS2);
            bits[r] |= a ? (1u << t) : 0u;
        }
    }

    int rc[RPT]; unsigned int off[RPT];
    #pragma unroll
    for (int r = 0; r < RPT; r++) {
        int d = irow[r] - j0;                        // keep bits with j > irow
        unsigned int m = (d < 0) ? 0xffffffffu : ((d >= JT - 1) ? 0u : (0xffffffffu << (d + 1)));
        bits[r] &= m;
        rc[r] = __popc(bits[r]);
        if (rc[r] > 0) off[r] = atomicAdd(&lcnt[gi[r]], (unsigned int)rc[r]);  // LDS atomic
    }
    __syncthreads();
    if (tid < NGROUPS && lcnt[tid] > 0)
        lbase[tid] = atomicAdd(&gcnt[(rt * NGROUPS + tid) * CPAD], lcnt[tid]);
    __syncthreads();

    #pragma unroll
    for (int r = 0; r < RPT; r++) {
        if (rc[r] > 0) {
            atomicAdd(&deg[irow[r]], rc[r]);
            unsigned int* reg = edges + (size_t)(rt * NGROUPS + gi[r]) * REGCAP;
            unsigned int pos = lbase[gi[r]] + off[r];
            unsigned int uhi = (unsigned int)irow[r] << 13;
            unsigned int b = bits[r];
            while (b) {
                int bb = __ffs(b) - 1;
                b &= b - 1;
                int j = j0 + bb;
                if (pos < REGCAP) reg[pos] = uhi | (unsigned int)j;
                pos++;
                atomicAdd(&deg[j], 1);
            }
        }
    }
}

// ---------------- per-group: load own slices + SV + rank + border + final ----
__global__ void __launch_bounds__(1024) k_group(
        const unsigned int* __restrict__ edges, const unsigned int* __restrict__ gcnt,
        const int* __restrict__ deg, const int* __restrict__ grp,
        const float* __restrict__ x, float* __restrict__ out) {
    __shared__ int spar[NPTS];                       // labels -> later ccid (32 KB)
    __shared__ int sbuf[NPTS];                       // scid then border-min (32 KB)
    __shared__ unsigned int eL[ELCAP];               // 32 KB
    __shared__ unsigned int eB[EBCAP];               // 8 KB
    __shared__ unsigned long long corebm[NPTS/64];   // 1 KB
    __shared__ unsigned long long gbm[NPTS/64];      // 1 KB
    __shared__ unsigned long long repbm[NPTS/64];    // 1 KB
    __shared__ int nlist[NLCAP];                     // 5 KB
    __shared__ int nNodes, nL, nB, sflag, wpart[16];

    int g = blockIdx.x;
    int tid = threadIdx.x, lane = tid & 63, wv = tid >> 6;

    if (tid == 0) { nNodes = 0; nL = 0; nB = 0; }
    for (int i = tid; i < NPTS; i += 1024) spar[i] = i;
    __syncthreads();
    // core / group bitmaps + compact node list (ballot, wave-aggregated)
    for (int w = wv; w < NPTS / 64; w += 16) {
        int i = w * 64 + lane;
        bool isc = deg[i] >= MIN_PTS;
        bool ing = grp[i] == g;
        unsigned long long cb = __ballot(isc);
        unsigned long long gb = __ballot(ing);
        if (lane == 0) { corebm[w] = cb; gbm[w] = gb; }
        int cnt = __popcll(gb);
        if (cnt) {
            int base = 0;
            if (lane == 0) base = atomicAdd(&nNodes, cnt);
            base = __shfl(base, 0);
            if (ing) nlist[base + __popcll(gb & ((1ull << lane) - 1ull))] = i;
        }
    }
    __syncthreads();

    auto corebit = [&](int v) -> bool { return (corebm[v >> 6] >> (v & 63)) & 1ull; };

    // load + classify this group's 8 band slices (core-core -> eL, mixed -> eB)
    for (int b = 0; b < BANDS; b++) {
        unsigned int Eu = gcnt[(b * NGROUPS + g) * CPAD];
        int E = (Eu > (unsigned)REGCAP) ? REGCAP : (int)Eu;
        const unsigned int* reg = edges + (size_t)(b * NGROUPS + g) * REGCAP;
        for (int e0 = 0; e0 < E; e0 += 1024) {
            int e = e0 + tid;
            unsigned int pk = (e < E) ? reg[e] : 0u;
            bool val = (e < E);
            int u = (int)(pk >> 13), v = (int)(pk & 8191u);
            bool cu = val && corebit(u), cv = val && corebit(v);
            bool isL = cu && cv;
            bool isB = val && (cu != cv);
            unsigned long long mL = __ballot(isL);
            int cL = __popcll(mL);
            int base = 0;
            if (cL) {
                if (lane == 0) base = atomicAdd(&nL, cL);
                base = __shfl(base, 0);
                if (isL) {
                    int idx = base + __popcll(mL & ((1ull << lane) - 1ull));
                    if (idx < ELCAP) eL[idx] = pk;
                }
            }
            unsigned long long mB = __ballot(isB);
            int cB = __popcll(mB);
            if (cB) {
                if (lane == 0) base = atomicAdd(&nB, cB);
                base = __shfl(base, 0);
                if (isB) {
                    int idx = base + __popcll(mB & ((1ull << lane) - 1ull));
                    if (idx < EBCAP) eB[idx] = pk;
                }
            }
        }
    }
    __syncthreads();
    int NN = nNodes; if (NN > NLCAP) NN = NLCAP;
    int NL = (nL > ELCAP) ? ELCAP : nL;
    int NB = (nB > EBCAP) ? EBCAP : nB;

    // SV rounds: hook-to-min (core-core edges) + pointer jump (group nodes)
    for (int r = 0; r < ROUNDS; r++) {
        if (tid == 0) sflag = 0;
        __syncthreads();
        for (int k = tid; k < NL; k += 1024) {
            unsigned int pk = eL[k];
            int u = (int)(pk >> 13), v = (int)(pk & 8191u);
            int a = spar[u], b2 = spar[v];
            if (a < b2)      { int old = atomicMin(&spar[v], a);  if (old > a)  sflag = 1; }
            else if (b2 < a) { int old = atomicMin(&spar[u], b2); if (old > b2) sflag = 1; }
        }
        __syncthreads();
        for (int k = tid; k < NN; k += 1024) {
            int i = nlist[k];
            int s = spar[i]; int s2 = spar[s];
            if (s2 < s) { spar[i] = s2; sflag = 1; }
        }
        __syncthreads();
        if (!sflag) break;
    }

    // rep bitmap (core, in-group, fixpoint) + hierarchical rank
    for (int w = wv; w < NPTS / 64; w += 16) {
        int i = w * 64 + lane;
        bool isr = ((corebm[w] & gbm[w]) >> lane & 1ull) && (spar[i] == i);
        unsigned long long bm = __ballot(isr);
        if (lane == 0) repbm[w] = bm;
    }
    __syncthreads();
    if (lane == 0) {
        int s = 0;
        #pragma unroll
        for (int k = 0; k < 8; k++) s += __popcll(repbm[wv * 8 + k]);
        wpart[wv] = s;
    }
    __syncthreads();
    if (tid == 0) {
        int acc = 0;
        #pragma unroll
        for (int w = 0; w < 16; w++) { int t = wpart[w]; wpart[w] = acc; acc += t; }
    }
    __syncthreads();
    {
        int running = wpart[wv];
        #pragma unroll
        for (int k = 0; k < 8; k++) {
            unsigned long long bb = repbm[wv * 8 + k];
            if ((bb >> lane) & 1ull)
                sbuf[(wv * 8 + k) * 64 + lane] = running + __popcll(bb & ((1ull << lane) - 1ull));
            running += __popcll(bb);
        }
    }
    __syncthreads();
    // ccid for group nodes -> overwrite spar; then sbuf -> border-min init
    int cc[2]; int ni[2];
    #pragma unroll
    for (int t = 0; t < 2; t++) {
        int k = tid + t * 1024;
        ni[t] = (k < NN) ? nlist[k] : -1;
        cc[t] = (ni[t] >= 0 && corebit(ni[t])) ? sbuf[spar[ni[t]]] : BIGC;
    }
    __syncthreads();
    #pragma unroll
    for (int t = 0; t < 2; t++) {
        if (ni[t] >= 0) { spar[ni[t]] = cc[t]; sbuf[ni[t]] = BIGC; }
    }
    __syncthreads();
    // border: min adjacent core cid for non-core endpoints
    for (int k = tid; k < NB; k += 1024) {
        unsigned int pk = eB[k];
        int u = (int)(pk >> 13), v = (int)(pk & 8191u);
        int cu = spar[u], cv = spar[v];
        if (cu == BIGC && cv != BIGC)      atomicMin(&sbuf[u], cv);
        else if (cv == BIGC && cu != BIGC) atomicMin(&sbuf[v], cu);
    }
    __syncthreads();
    // final labels + clustered output for this group's nodes
    #pragma unroll
    for (int t = 0; t < 2; t++) {
        int i = ni[t];
        if (i < 0) continue;
        int c = spar[i];
        int lbl = (c != BIGC) ? c : ((sbuf[i] < BIGC) ? sbuf[i] : -1);
        out[i] = (float)lbl;
        const float* r = x + (size_t)i * XCOLS;
        float* o = out + NPTS + (size_t)i * 5;
        bool keep = lbl >= 0;
        #pragma unroll
        for (int c5 = 0; c5 < 5; c5++) o[c5] = keep ? r[c5] : 0.0f;
    }
}

extern "C" void kernel_launch(void* const* d_in, const int* in_sizes, int n_in,
                              void* d_out, int out_size, void* d_ws, size_t ws_size,
                              hipStream_t stream) {
    const float* x = (const float*)d_in[0];
    float* out = (float*)d_out;
    char* ws = (char*)d_ws;

    // workspace layout (~2.9 MB)
    float4* q            = (float4*)(ws);                   // 131072 B
    int* grp             = (int*)(ws + 131072);             // 32768
    int* deg             = (int*)(ws + 163840);             // 32768
    unsigned int* gcnt   = (unsigned int*)(ws + 196608);    // 80*64*4 = 20480
    unsigned int* edges  = (unsigned int*)(ws + 217088);    // 80*8192*4 = 2.62 MB

    k_setup <<<NPTS / 256, 256, 0, stream>>>(x, q, grp, deg, gcnt);
    k_adj   <<<BANDS * 256, 256, 0, stream>>>(q, grp, edges, gcnt, deg);
    k_group <<<NGROUPS, 1024, 0, stream>>>(edges, gcnt, deg, grp, x, out);
}